// Round 12
// baseline (163.986 us; speedup 1.0000x reference)
//
#include <hip/hip_runtime.h>

// Problem constants from setup_inputs(): shape (64, 16, 64, 64), fp32, kern=2.
#define N_ 64
#define C_ 16
#define H_ 64
#define W_ 64

// pair_kernel tiling: 4 i-rows x 8 j-rows per tile; D split into 8 block-chunks
// of 2048, each processed as 2 sequential sub-chunks of 1024 (float4/thread).
// Rationale (R8/R10/R11): wall time tracks block count via start-of-block load
// stalls (~0.7us each); 4352 blocks was better than 8704; here 2176 blocks with
// an internal sub-chunk loop keeps R8's exact register/instruction structure
// (VGPR=68) while halving the number of cold starts.
// tri sets (vaa, vbb): i-tile g (rows 4g..4g+3) needs j-tiles 0..(g>>1)
//   -> sum over g=0..15 of (g>>1)+1 = 72 tiles per set
// vab (full): 16 i-tiles x 8 j-tiles = 128 tiles. TILES = 72*2 + 128 = 272.
#define TRI_TILES 72
#define TILES 272
#define DCHUNKS 8
#define SUBCHUNKS 2
#define PAIR_BLOCKS (TILES * DCHUNKS)   // 2176

// NUMERICS: ws stores var' = var * 2ln2. Then exp(-0.5 d^2/v)/sqrt(v)
//   = exp2(-(d*rsq(v'))^2) * rsq(v') * sqrt(2ln2);
// sqrt(2ln2)=1.1774100 folds into the per-block partial.
// TERM = add, rsq, sub, mul, mul(neg src-mod folds), exp2, fma:
// ~4 VALU + 2 quarter-rate transc -> transc pipe is ~80% of issue cycles.
#define TWO_LN2   1.3862943611198906f
#define SQRT_2LN2 1.1774100225154747f

// ws layout (floats): [0..Np) mu_a | [Np..2Np) var'_a | [2Np..3Np) mu_b |
// [3Np..4Np) var'_b | [4Np..4Np+PAIR_BLOCKS) per-block partials.
// R7 lesson: contended single-address atomicAdd serializes (~6ns/block).
// R9 lesson: agent-scope acq/rel fences inside the kernel emit L2 wb/inv ->
// j-stream reuse dies. Separate reduce launch gets coherence for free.

__global__ __launch_bounds__(256) void pool_kernel(
    const float* __restrict__ mu_a, const float* __restrict__ lv_a,
    const float* __restrict__ mu_b, const float* __restrict__ lv_b,
    const int* __restrict__ kern_p, float* __restrict__ ws) {
    const int k = kern_p[0];
    const float LOG2E = 1.44269504088896f;

    if (k == 2) {
        // Fast path: 4 contiguous pooled outputs per thread, all-shift indexing.
        const int Np = (N_ * C_ * H_ * W_) >> 2;  // 1048576
        const int Q  = Np >> 2;                   // 262144 quads per array
        const int total = 4 * Q;
        for (int g = blockIdx.x * blockDim.x + threadIdx.x; g < total;
             g += gridDim.x * blockDim.x) {
            const int a  = g >> 18;               // log2(Q) = 18
            const int r4 = g & (Q - 1);
            const int pw4 = (r4 & 7) << 2;        // Wp=32 -> 8 quads/row
            const int t   = r4 >> 3;
            const int ph  = t & 31;               // Hp=32
            const int nc  = t >> 5;
            const float* src = (a == 0) ? mu_a : (a == 1) ? lv_a : (a == 2) ? mu_b : lv_b;
            const bool is_var = (a & 1);
            const float* p0 = src + nc * (H_ * W_) + (ph * 2) * W_ + pw4 * 2;
            float4 r0a = *(const float4*)(p0);
            float4 r0b = *(const float4*)(p0 + 4);
            float4 r1a = *(const float4*)(p0 + W_);
            float4 r1b = *(const float4*)(p0 + W_ + 4);
            float o0, o1, o2, o3;
            if (is_var) {
#define E_(x) __builtin_amdgcn_exp2f((x) * LOG2E)
                o0 = E_(r0a.x) + E_(r0a.y) + E_(r1a.x) + E_(r1a.y);
                o1 = E_(r0a.z) + E_(r0a.w) + E_(r1a.z) + E_(r1a.w);
                o2 = E_(r0b.x) + E_(r0b.y) + E_(r1b.x) + E_(r1b.y);
                o3 = E_(r0b.z) + E_(r0b.w) + E_(r1b.z) + E_(r1b.w);
#undef E_
                const float s = (1.0f / 16.0f) * TWO_LN2;  // 1/k^4 * 2ln2
                o0 *= s; o1 *= s; o2 *= s; o3 *= s;
            } else {
                o0 = r0a.x + r0a.y + r1a.x + r1a.y;
                o1 = r0a.z + r0a.w + r1a.z + r1a.w;
                o2 = r0b.x + r0b.y + r1b.x + r1b.y;
                o3 = r0b.z + r0b.w + r1b.z + r1b.w;
                const float s = 0.25f;            // 1/k^2
                o0 *= s; o1 *= s; o2 *= s; o3 *= s;
            }
            *(float4*)(ws + (size_t)a * Np + (size_t)r4 * 4) = make_float4(o0, o1, o2, o3);
        }
    } else {
        // Generic fallback (any k dividing 64).
        const int Hp = H_ / k, Wp = W_ / k;
        const int Np = N_ * C_ * Hp * Wp;
        const float inv_k2 = 1.0f / (float)(k * k);
        const float inv_k4 = inv_k2 * inv_k2 * TWO_LN2;   // fold var pre-scale
        const int total = 4 * Np;
        for (int p = blockIdx.x * blockDim.x + threadIdx.x; p < total;
             p += gridDim.x * blockDim.x) {
            const int a  = p / Np;
            const int r  = p - a * Np;
            const int pw = r % Wp;
            const int t1 = r / Wp;
            const int ph = t1 % Hp;
            const int nc = t1 / Hp;
            const float* src = (a == 0) ? mu_a : (a == 1) ? lv_a : (a == 2) ? mu_b : lv_b;
            const bool is_var = (a & 1);
            const int base = nc * (H_ * W_) + (ph * k) * W_ + (pw * k);
            float s = 0.0f;
            for (int dy = 0; dy < k; ++dy) {
                const float* row = src + base + dy * W_;
                for (int dx = 0; dx < k; ++dx) {
                    float x = row[dx];
                    s += is_var ? __builtin_amdgcn_exp2f(x * LOG2E) : x;
                }
            }
            ws[(size_t)a * Np + r] = s * (is_var ? inv_k4 : inv_k2);
        }
    }
}

// block = (tile t, chunk c): 4 i-rows register-resident (1 float4 mu + var' each,
// reloaded per sub-chunk), 8 j-rows streamed. Plain stores; no atomics/fences.
// NOTE: no min-waves clause — R3 showed forcing the register budget spills.
__global__ __launch_bounds__(256) void pair_kernel(float* __restrict__ ws,
                                                   const int* __restrict__ kern_p) {
    const int k = kern_p[0];
    const int D  = C_ * (H_ / k) * (W_ / k);
    const int Np = N_ * D;

    const float* mu_a = ws;
    const float* va   = ws + (size_t)Np;
    const float* mu_b = ws + (size_t)2 * Np;
    const float* vb   = ws + (size_t)3 * Np;
    float* partials   = ws + (size_t)4 * Np;

    // ---- decode block -> (set, i-tile, j-tile, chunk) ----
    const int c = blockIdx.x & (DCHUNKS - 1);
    const int t = blockIdx.x >> 3;           // DCHUNKS == 8
    int set, it, jt;
    if (t >= 2 * TRI_TILES) {
        set = 2;
        const int tt = t - 2 * TRI_TILES;
        it = tt >> 3;
        jt = tt & 7;
    } else {
        set = (t >= TRI_TILES) ? 1 : 0;
        const int tt = set ? (t - TRI_TILES) : t;
        int g = 0, cum = 0;
        while (cum + (g >> 1) + 1 <= tt) { cum += (g >> 1) + 1; ++g; }
        it = g;
        jt = tt - cum;
    }
    const int i0 = it * 4, j0 = jt * 8;

    const float *mu1, *v1, *mu2, *v2;
    if (set == 0)      { mu1 = mu2 = mu_a; v1 = v2 = va; }
    else if (set == 1) { mu1 = mu2 = mu_b; v1 = v2 = vb; }
    else               { mu1 = mu_a; v1 = va; mu2 = mu_b; v2 = vb; }

#define TERM(acc, mx1, sx1, mx2, sx2)                                  \
    {                                                                  \
        float v  = (sx1) + (sx2);                                      \
        float rs = __builtin_amdgcn_rsqf(v);                           \
        float d  = (mx1) - (mx2);                                      \
        float t_ = d * rs;                                             \
        float e  = __builtin_amdgcn_exp2f(-(t_ * t_));                 \
        acc = fmaf(e, rs, acc);                                        \
    }

    float accs[4][8];
    #pragma unroll
    for (int ir = 0; ir < 4; ++ir)
        #pragma unroll
        for (int j8 = 0; j8 < 8; ++j8) accs[ir][j8] = 0.0f;

    if (D == 16384) {
        // Fast path: block-chunk = 2048 elems, 2 sub-chunks of 1024
        // (256 threads x 1 float4 each). i-regs reused across sub-chunks.
        #pragma unroll
        for (int sc = 0; sc < SUBCHUNKS; ++sc) {
            const int base = (c << 11) + (sc << 10) + ((int)threadIdx.x << 2);
            float4 im[4], iv[4];
            #pragma unroll
            for (int ir = 0; ir < 4; ++ir) {
                im[ir] = *(const float4*)(mu1 + (size_t)(i0 + ir) * 16384 + base);
                iv[ir] = *(const float4*)(v1  + (size_t)(i0 + ir) * 16384 + base);
            }
            #pragma unroll
            for (int j8 = 0; j8 < 8; ++j8) {
                const float4 jm = *(const float4*)(mu2 + (size_t)(j0 + j8) * 16384 + base);
                const float4 jv = *(const float4*)(v2  + (size_t)(j0 + j8) * 16384 + base);
                #pragma unroll
                for (int ir = 0; ir < 4; ++ir) {
                    TERM(accs[ir][j8], im[ir].x, iv[ir].x, jm.x, jv.x)
                    TERM(accs[ir][j8], im[ir].y, iv[ir].y, jm.y, jv.y)
                    TERM(accs[ir][j8], im[ir].z, iv[ir].z, jm.z, jv.z)
                    TERM(accs[ir][j8], im[ir].w, iv[ir].w, jm.w, jv.w)
                }
            }
        }
    } else {
        // Generic fallback: chunk c covers [c*D/8, (c+1)*D/8), scalar loads.
        const int lo = (c * D) / DCHUNKS, hi = ((c + 1) * D) / DCHUNKS;
        for (int e = lo + (int)threadIdx.x; e < hi; e += 256) {
            #pragma unroll
            for (int j8 = 0; j8 < 8; ++j8) {
                const float mj = mu2[(size_t)(j0 + j8) * D + e];
                const float vj = v2 [(size_t)(j0 + j8) * D + e];
                #pragma unroll
                for (int ir = 0; ir < 4; ++ir) {
                    const float mi = mu1[(size_t)(i0 + ir) * D + e];
                    const float vi = v1 [(size_t)(i0 + ir) * D + e];
                    TERM(accs[ir][j8], mi, vi, mj, vj)
                }
            }
        }
    }
#undef TERM

    float tot = 0.0f;
    #pragma unroll
    for (int ir = 0; ir < 4; ++ir) {
        #pragma unroll
        for (int j8 = 0; j8 < 8; ++j8) {
            float w;
            if (set == 2) w = -2.0f;
            else {
                const int ii = i0 + ir, jj = j0 + j8;
                w = (jj > ii) ? 0.0f : (jj == ii) ? 1.0f : 2.0f;
            }
            tot = fmaf(w, accs[ir][j8], tot);
        }
    }
    tot *= SQRT_2LN2;   // fold the var'-prescale correction once

    for (int off = 32; off > 0; off >>= 1)
        tot += __shfl_down(tot, off, 64);
    __shared__ float wsum[4];
    const int lane = threadIdx.x & 63;
    const int wid  = threadIdx.x >> 6;
    if (lane == 0) wsum[wid] = tot;
    __syncthreads();
    if (threadIdx.x == 0) {
        partials[blockIdx.x] = wsum[0] + wsum[1] + wsum[2] + wsum[3];
    }
}

// Single block: sum the PAIR_BLOCKS partials into out[0].
__global__ __launch_bounds__(256) void reduce_kernel(const float* __restrict__ ws,
                                                     const int* __restrict__ kern_p,
                                                     float* __restrict__ out) {
    const int k = kern_p[0];
    const int D  = C_ * (H_ / k) * (W_ / k);
    const int Np = N_ * D;
    const float* partials = ws + (size_t)4 * Np;

    float s = 0.0f;
    for (int p = threadIdx.x; p < PAIR_BLOCKS; p += 256) s += partials[p];
    for (int off = 32; off > 0; off >>= 1)
        s += __shfl_down(s, off, 64);
    __shared__ float wsum[4];
    const int lane = threadIdx.x & 63;
    const int wid  = threadIdx.x >> 6;
    if (lane == 0) wsum[wid] = s;
    __syncthreads();
    if (threadIdx.x == 0) out[0] = wsum[0] + wsum[1] + wsum[2] + wsum[3];
}

extern "C" void kernel_launch(void* const* d_in, const int* in_sizes, int n_in,
                              void* d_out, int out_size, void* d_ws, size_t ws_size,
                              hipStream_t stream) {
    const float* mu_a = (const float*)d_in[0];
    const float* lv_a = (const float*)d_in[1];
    const float* mu_b = (const float*)d_in[2];
    const float* lv_b = (const float*)d_in[3];
    const int*   kern = (const int*)d_in[4];
    float* out = (float*)d_out;
    float* ws  = (float*)d_ws;

    pool_kernel<<<4096, 256, 0, stream>>>(mu_a, lv_a, mu_b, lv_b, kern, ws);
    pair_kernel<<<PAIR_BLOCKS, 256, 0, stream>>>(ws, kern);
    reduce_kernel<<<1, 256, 0, stream>>>(ws, kern, out);
}

// Round 13
// 145.161 us; speedup vs baseline: 1.1297x; 1.1297x over previous
//
#include <hip/hip_runtime.h>

// Problem constants from setup_inputs(): shape (64, 16, 64, 64), fp32, kern=2.
#define N_ 64
#define C_ 16
#define H_ 64
#define W_ 64

// pair_kernel tiling: 4 i-rows x 8 j-rows per tile; D split into 8 block-chunks
// of 2048, each processed as 2 SEQUENTIAL sub-chunks of 1024 (float4/thread).
// #pragma unroll 1 on the sub-chunk loop is load-bearing: R12's full unroll let
// the compiler pipeline both sub-chunks -> VGPR 164, occupancy 9.6%, 66us.
// With unroll 1 the live set is per-sub-chunk (R8's ~68 VGPR) while halving
// the number of block cold-starts vs R8 (2176 blocks, 8.5/CU). c == XCD
// (bx % 8 = c), so each XCD's L2 serves exactly one 2048-col chunk (~2 MB).
// tri sets (vaa, vbb): i-tile g (rows 4g..4g+3) needs j-tiles 0..(g>>1)
//   -> sum over g=0..15 of (g>>1)+1 = 72 tiles per set
// vab (full): 16 i-tiles x 8 j-tiles = 128 tiles. TILES = 72*2 + 128 = 272.
#define TRI_TILES 72
#define TILES 272
#define DCHUNKS 8
#define SUBCHUNKS 2
#define PAIR_BLOCKS (TILES * DCHUNKS)   // 2176

// NUMERICS: ws stores var' = var * 2ln2. Then exp(-0.5 d^2/v)/sqrt(v)
//   = exp2(-(d*rsq(v'))^2) * rsq(v') * sqrt(2ln2);
// sqrt(2ln2)=1.1774100 folds into the per-block partial.
// TERM = add, rsq, sub, mul, mul(neg folds to src-mod), exp2, fma:
// ~4 VALU + 2 quarter-rate transc -> transc pipe ~80% of issue cycles
// (busy floor ~34.5us, invariant across R8/R10/R11 configs).
#define TWO_LN2   1.3862943611198906f
#define SQRT_2LN2 1.1774100225154747f

// ws layout (floats): [0..Np) mu_a | [Np..2Np) var'_a | [2Np..3Np) mu_b |
// [3Np..4Np) var'_b | [4Np..4Np+PAIR_BLOCKS) per-block partials.
// R7 lesson: contended single-address atomicAdd serializes (~6ns/block).
// R9 lesson: agent-scope acq/rel fences inside the kernel emit L2 wb/inv ->
// j-stream reuse dies. Separate reduce launch gets coherence for free.

__global__ __launch_bounds__(256) void pool_kernel(
    const float* __restrict__ mu_a, const float* __restrict__ lv_a,
    const float* __restrict__ mu_b, const float* __restrict__ lv_b,
    const int* __restrict__ kern_p, float* __restrict__ ws) {
    const int k = kern_p[0];
    const float LOG2E = 1.44269504088896f;

    if (k == 2) {
        // Fast path: 4 contiguous pooled outputs per thread, all-shift indexing.
        const int Np = (N_ * C_ * H_ * W_) >> 2;  // 1048576
        const int Q  = Np >> 2;                   // 262144 quads per array
        const int total = 4 * Q;
        for (int g = blockIdx.x * blockDim.x + threadIdx.x; g < total;
             g += gridDim.x * blockDim.x) {
            const int a  = g >> 18;               // log2(Q) = 18
            const int r4 = g & (Q - 1);
            const int pw4 = (r4 & 7) << 2;        // Wp=32 -> 8 quads/row
            const int t   = r4 >> 3;
            const int ph  = t & 31;               // Hp=32
            const int nc  = t >> 5;
            const float* src = (a == 0) ? mu_a : (a == 1) ? lv_a : (a == 2) ? mu_b : lv_b;
            const bool is_var = (a & 1);
            const float* p0 = src + nc * (H_ * W_) + (ph * 2) * W_ + pw4 * 2;
            float4 r0a = *(const float4*)(p0);
            float4 r0b = *(const float4*)(p0 + 4);
            float4 r1a = *(const float4*)(p0 + W_);
            float4 r1b = *(const float4*)(p0 + W_ + 4);
            float o0, o1, o2, o3;
            if (is_var) {
#define E_(x) __builtin_amdgcn_exp2f((x) * LOG2E)
                o0 = E_(r0a.x) + E_(r0a.y) + E_(r1a.x) + E_(r1a.y);
                o1 = E_(r0a.z) + E_(r0a.w) + E_(r1a.z) + E_(r1a.w);
                o2 = E_(r0b.x) + E_(r0b.y) + E_(r1b.x) + E_(r1b.y);
                o3 = E_(r0b.z) + E_(r0b.w) + E_(r1b.z) + E_(r1b.w);
#undef E_
                const float s = (1.0f / 16.0f) * TWO_LN2;  // 1/k^4 * 2ln2
                o0 *= s; o1 *= s; o2 *= s; o3 *= s;
            } else {
                o0 = r0a.x + r0a.y + r1a.x + r1a.y;
                o1 = r0a.z + r0a.w + r1a.z + r1a.w;
                o2 = r0b.x + r0b.y + r1b.x + r1b.y;
                o3 = r0b.z + r0b.w + r1b.z + r1b.w;
                const float s = 0.25f;            // 1/k^2
                o0 *= s; o1 *= s; o2 *= s; o3 *= s;
            }
            *(float4*)(ws + (size_t)a * Np + (size_t)r4 * 4) = make_float4(o0, o1, o2, o3);
        }
    } else {
        // Generic fallback (any k dividing 64).
        const int Hp = H_ / k, Wp = W_ / k;
        const int Np = N_ * C_ * Hp * Wp;
        const float inv_k2 = 1.0f / (float)(k * k);
        const float inv_k4 = inv_k2 * inv_k2 * TWO_LN2;   // fold var pre-scale
        const int total = 4 * Np;
        for (int p = blockIdx.x * blockDim.x + threadIdx.x; p < total;
             p += gridDim.x * blockDim.x) {
            const int a  = p / Np;
            const int r  = p - a * Np;
            const int pw = r % Wp;
            const int t1 = r / Wp;
            const int ph = t1 % Hp;
            const int nc = t1 / Hp;
            const float* src = (a == 0) ? mu_a : (a == 1) ? lv_a : (a == 2) ? mu_b : lv_b;
            const bool is_var = (a & 1);
            const int base = nc * (H_ * W_) + (ph * k) * W_ + (pw * k);
            float s = 0.0f;
            for (int dy = 0; dy < k; ++dy) {
                const float* row = src + base + dy * W_;
                for (int dx = 0; dx < k; ++dx) {
                    float x = row[dx];
                    s += is_var ? __builtin_amdgcn_exp2f(x * LOG2E) : x;
                }
            }
            ws[(size_t)a * Np + r] = s * (is_var ? inv_k4 : inv_k2);
        }
    }
}

// block = (tile t, chunk c): 4 i-rows register-resident (1 float4 mu + var' each,
// reloaded per sub-chunk), 8 j-rows streamed. Plain stores; no atomics/fences.
// NOTE: no min-waves clause — R3 showed forcing the register budget spills.
__global__ __launch_bounds__(256) void pair_kernel(float* __restrict__ ws,
                                                   const int* __restrict__ kern_p) {
    const int k = kern_p[0];
    const int D  = C_ * (H_ / k) * (W_ / k);
    const int Np = N_ * D;

    const float* mu_a = ws;
    const float* va   = ws + (size_t)Np;
    const float* mu_b = ws + (size_t)2 * Np;
    const float* vb   = ws + (size_t)3 * Np;
    float* partials   = ws + (size_t)4 * Np;

    // ---- decode block -> (set, i-tile, j-tile, chunk) ----
    const int c = blockIdx.x & (DCHUNKS - 1);
    const int t = blockIdx.x >> 3;           // DCHUNKS == 8
    int set, it, jt;
    if (t >= 2 * TRI_TILES) {
        set = 2;
        const int tt = t - 2 * TRI_TILES;
        it = tt >> 3;
        jt = tt & 7;
    } else {
        set = (t >= TRI_TILES) ? 1 : 0;
        const int tt = set ? (t - TRI_TILES) : t;
        int g = 0, cum = 0;
        while (cum + (g >> 1) + 1 <= tt) { cum += (g >> 1) + 1; ++g; }
        it = g;
        jt = tt - cum;
    }
    const int i0 = it * 4, j0 = jt * 8;

    const float *mu1, *v1, *mu2, *v2;
    if (set == 0)      { mu1 = mu2 = mu_a; v1 = v2 = va; }
    else if (set == 1) { mu1 = mu2 = mu_b; v1 = v2 = vb; }
    else               { mu1 = mu_a; v1 = va; mu2 = mu_b; v2 = vb; }

#define TERM(acc, mx1, sx1, mx2, sx2)                                  \
    {                                                                  \
        float v  = (sx1) + (sx2);                                      \
        float rs = __builtin_amdgcn_rsqf(v);                           \
        float d  = (mx1) - (mx2);                                      \
        float t_ = d * rs;                                             \
        float e  = __builtin_amdgcn_exp2f(-(t_ * t_));                 \
        acc = fmaf(e, rs, acc);                                        \
    }

    float accs[4][8];
    #pragma unroll
    for (int ir = 0; ir < 4; ++ir)
        #pragma unroll
        for (int j8 = 0; j8 < 8; ++j8) accs[ir][j8] = 0.0f;

    if (D == 16384) {
        // Fast path: block-chunk = 2048 elems, 2 sequential sub-chunks of 1024
        // (256 threads x 1 float4 each). unroll 1 is REQUIRED — see header.
        #pragma unroll 1
        for (int sc = 0; sc < SUBCHUNKS; ++sc) {
            const int base = (c << 11) + (sc << 10) + ((int)threadIdx.x << 2);
            float4 im[4], iv[4];
            #pragma unroll
            for (int ir = 0; ir < 4; ++ir) {
                im[ir] = *(const float4*)(mu1 + (size_t)(i0 + ir) * 16384 + base);
                iv[ir] = *(const float4*)(v1  + (size_t)(i0 + ir) * 16384 + base);
            }
            #pragma unroll
            for (int j8 = 0; j8 < 8; ++j8) {
                const float4 jm = *(const float4*)(mu2 + (size_t)(j0 + j8) * 16384 + base);
                const float4 jv = *(const float4*)(v2  + (size_t)(j0 + j8) * 16384 + base);
                #pragma unroll
                for (int ir = 0; ir < 4; ++ir) {
                    TERM(accs[ir][j8], im[ir].x, iv[ir].x, jm.x, jv.x)
                    TERM(accs[ir][j8], im[ir].y, iv[ir].y, jm.y, jv.y)
                    TERM(accs[ir][j8], im[ir].z, iv[ir].z, jm.z, jv.z)
                    TERM(accs[ir][j8], im[ir].w, iv[ir].w, jm.w, jv.w)
                }
            }
        }
    } else {
        // Generic fallback: chunk c covers [c*D/8, (c+1)*D/8), scalar loads.
        const int lo = (c * D) / DCHUNKS, hi = ((c + 1) * D) / DCHUNKS;
        for (int e = lo + (int)threadIdx.x; e < hi; e += 256) {
            #pragma unroll
            for (int j8 = 0; j8 < 8; ++j8) {
                const float mj = mu2[(size_t)(j0 + j8) * D + e];
                const float vj = v2 [(size_t)(j0 + j8) * D + e];
                #pragma unroll
                for (int ir = 0; ir < 4; ++ir) {
                    const float mi = mu1[(size_t)(i0 + ir) * D + e];
                    const float vi = v1 [(size_t)(i0 + ir) * D + e];
                    TERM(accs[ir][j8], mi, vi, mj, vj)
                }
            }
        }
    }
#undef TERM

    float tot = 0.0f;
    #pragma unroll
    for (int ir = 0; ir < 4; ++ir) {
        #pragma unroll
        for (int j8 = 0; j8 < 8; ++j8) {
            float w;
            if (set == 2) w = -2.0f;
            else {
                const int ii = i0 + ir, jj = j0 + j8;
                w = (jj > ii) ? 0.0f : (jj == ii) ? 1.0f : 2.0f;
            }
            tot = fmaf(w, accs[ir][j8], tot);
        }
    }
    tot *= SQRT_2LN2;   // fold the var'-prescale correction once

    for (int off = 32; off > 0; off >>= 1)
        tot += __shfl_down(tot, off, 64);
    __shared__ float wsum[4];
    const int lane = threadIdx.x & 63;
    const int wid  = threadIdx.x >> 6;
    if (lane == 0) wsum[wid] = tot;
    __syncthreads();
    if (threadIdx.x == 0) {
        partials[blockIdx.x] = wsum[0] + wsum[1] + wsum[2] + wsum[3];
    }
}

// Single block: sum the PAIR_BLOCKS partials into out[0].
__global__ __launch_bounds__(256) void reduce_kernel(const float* __restrict__ ws,
                                                     const int* __restrict__ kern_p,
                                                     float* __restrict__ out) {
    const int k = kern_p[0];
    const int D  = C_ * (H_ / k) * (W_ / k);
    const int Np = N_ * D;
    const float* partials = ws + (size_t)4 * Np;

    float s = 0.0f;
    for (int p = threadIdx.x; p < PAIR_BLOCKS; p += 256) s += partials[p];
    for (int off = 32; off > 0; off >>= 1)
        s += __shfl_down(s, off, 64);
    __shared__ float wsum[4];
    const int lane = threadIdx.x & 63;
    const int wid  = threadIdx.x >> 6;
    if (lane == 0) wsum[wid] = s;
    __syncthreads();
    if (threadIdx.x == 0) out[0] = wsum[0] + wsum[1] + wsum[2] + wsum[3];
}

extern "C" void kernel_launch(void* const* d_in, const int* in_sizes, int n_in,
                              void* d_out, int out_size, void* d_ws, size_t ws_size,
                              hipStream_t stream) {
    const float* mu_a = (const float*)d_in[0];
    const float* lv_a = (const float*)d_in[1];
    const float* mu_b = (const float*)d_in[2];
    const float* lv_b = (const float*)d_in[3];
    const int*   kern = (const int*)d_in[4];
    float* out = (float*)d_out;
    float* ws  = (float*)d_ws;

    pool_kernel<<<4096, 256, 0, stream>>>(mu_a, lv_a, mu_b, lv_b, kern, ws);
    pair_kernel<<<PAIR_BLOCKS, 256, 0, stream>>>(ws, kern);
    reduce_kernel<<<1, 256, 0, stream>>>(ws, kern, out);
}